// Round 8
// baseline (128.080 us; speedup 1.0000x reference)
//
#include <hip/hip_runtime.h>

// Problem constants
#define B_ 4
#define C_ 64
#define F_ 64
#define T_ 128
#define IC_ 32
#define N_ 8192
#define M_ 2048

// Scratch layout (float units; all fp32 intermediates)
#define OFF_U      0           // B*N
#define OFF_PSI2   32768       // B*M*IC, layout [b][m][c]
#define OFF_V      294912      // B*M
#define OFF_VS     303104      // B*M sorted v (descending)
#define OFF_Q01    311296      // B*2049*64 float2 (z-prefix, vz-prefix), layout [b][k][o]
#define WS_FLOATS  1360384     // 5.44 MB static device scratch

__device__ __align__(16) float g_ws[WS_FLOATS];
__device__ int g_perm[B_ * M_];

// ---------------------------------------------------------------------------
// Kernel 1: psi/phi conv + 2x2 maxpool -> psi2, v; collapsed theta -> u
// 512 blocks x 256 thr. block=(b, fh, col-quarter of 32 cols).
// Mapping O=2 o/thread, P=4 positions (4 cols x 1 row): 128 ds_read_b128 per
// thread (64 x + 64 w) vs 160 in the O=1,P=8 mapping. Pool row-combine via
// in-wave shfl_xor(16).
// ---------------------------------------------------------------------------
__global__ __launch_bounds__(256) void k1(
    const float* __restrict__ x,
    const float* __restrict__ psi_w, const float* __restrict__ psi_b,
    const float* __restrict__ theta_w, const float* __restrict__ theta_b,
    const float* __restrict__ phi_w, const float* __restrict__ phi_b,
    const float* __restrict__ h0_w, const float* __restrict__ h1_w,
    const float* __restrict__ h2_w)
{
    float* __restrict__ ws = g_ws;
    __shared__ __align__(16) float xs[4096];   // [c][r2(2)][col(32)]
    __shared__ __align__(16) float pw[2048];   // [(c4*32 + o)*4 + j]
    __shared__ __align__(16) float fw[2048];
    __shared__ float wt_l[64];

    const int tid = threadIdx.x;
    const int bid = blockIdx.x;
    const int b = bid >> 7;
    const int rem = bid & 127;
    const int fh = rem >> 2;        // [0,32)
    const int q = rem & 3;          // col-quarter [0,4)
    const int c0 = q * 32;

    // stage x tile (float4): 64 ch x rows {2fh,2fh+1} x cols [c0,c0+32)
    for (int idx = tid; idx < 1024; idx += 256) {
        const int c = idx >> 4, r2 = (idx >> 3) & 1, t4 = idx & 7;
        const float4 v = *(const float4*)&x[(((size_t)b * 64 + c) * 64 + (2 * fh + r2)) * 128 + c0 + 4 * t4];
        *(float4*)&xs[c * 64 + r2 * 32 + 4 * t4] = v;
    }
    // stage weights in float4-grouped layout
    for (int idx = tid; idx < 2048; idx += 256) {
        const int c4 = idx >> 7, o = (idx >> 2) & 31, j = idx & 3;
        pw[idx] = psi_w[o * 64 + 4 * c4 + j];
        fw[idx] = phi_w[o * 64 + 4 * c4 + j];
    }
    if (tid < 64) {
        float acc = 0.f;
        for (int o2 = 0; o2 < 32; ++o2)
            acc += h0_w[o2] * theta_w[o2 * 64 + tid];
        wt_l[tid] = acc;
    }
    __syncthreads();

    const float h20 = h2_w[0], h21 = h2_w[1];

    // conv + pool: thread = (o16 in [0,16), r in {0,1}, g in [0,8)); this
    // thread covers o = {o16, o16+16}, row r, cols 4g..4g+3.
    {
        const int o16 = tid & 15;
        const int r   = (tid >> 4) & 1;
        const int g   = tid >> 5;
        const float4* pw4 = (const float4*)pw;
        const float4* fw4 = (const float4*)fw;
        const float4* xs4 = (const float4*)xs;
        float spa[4] = {0,0,0,0}, spb[4] = {0,0,0,0};   // psi: o16, o16+16
        float sfa[4] = {0,0,0,0}, sfb[4] = {0,0,0,0};   // phi: o16, o16+16
        for (int c4 = 0; c4 < 16; ++c4) {
            const float4 pva = pw4[c4 * 32 + o16];
            const float4 pvb = pw4[c4 * 32 + o16 + 16];
            const float4 fva = fw4[c4 * 32 + o16];
            const float4 fvb = fw4[c4 * 32 + o16 + 16];
            const float* pvaf = (const float*)&pva;
            const float* pvbf = (const float*)&pvb;
            const float* fvaf = (const float*)&fva;
            const float* fvbf = (const float*)&fvb;
#pragma unroll
            for (int j = 0; j < 4; ++j) {
                const int c = 4 * c4 + j;
                const float4 xv = xs4[c * 16 + r * 8 + g];   // cols 4g..4g+3, row r
                const float wa = pvaf[j], wb = pvbf[j];
                const float fa = fvaf[j], fb = fvbf[j];
                spa[0] += wa * xv.x; spa[1] += wa * xv.y; spa[2] += wa * xv.z; spa[3] += wa * xv.w;
                spb[0] += wb * xv.x; spb[1] += wb * xv.y; spb[2] += wb * xv.z; spb[3] += wb * xv.w;
                sfa[0] += fa * xv.x; sfa[1] += fa * xv.y; sfa[2] += fa * xv.z; sfa[3] += fa * xv.w;
                sfb[0] += fb * xv.x; sfb[1] += fb * xv.y; sfb[2] += fb * xv.z; sfb[3] += fb * xv.w;
            }
        }
        const float pba = psi_b[o16], pbb = psi_b[o16 + 16];
        const float fba = phi_b[o16], fbb = phi_b[o16 + 16];
        const float h1a = h1_w[o16], h1b = h1_w[o16 + 16];
#pragma unroll
        for (int h = 0; h < 2; ++h) {
            // row-partial max over col-pair {2h, 2h+1}
            float mpa = fmaxf(spa[2 * h], spa[2 * h + 1]);
            float mpb = fmaxf(spb[2 * h], spb[2 * h + 1]);
            float mfa = fmaxf(sfa[2 * h], sfa[2 * h + 1]);
            float mfb = fmaxf(sfb[2 * h], sfb[2 * h + 1]);
            // combine the two rows: partner lane differs in bit 4 (r)
            mpa = fmaxf(mpa, __shfl_xor(mpa, 16, 64));
            mpb = fmaxf(mpb, __shfl_xor(mpb, 16, 64));
            mfa = fmaxf(mfa, __shfl_xor(mfa, 16, 64));
            mfb = fmaxf(mfb, __shfl_xor(mfb, 16, 64));
            const float psiva = mpa + pba, psivb = mpb + pbb;
            const float phiva = mfa + fba, phivb = mfb + fbb;
            const int hc = 2 * g + h;
            const int m = fh * 64 + q * 16 + hc;
            if (r == 0) {
                float* dst = ws + OFF_PSI2 + ((size_t)b * 2048 + m) * 32;
                dst[o16] = psiva;
                dst[o16 + 16] = psivb;
            }
            // v[b,m]: butterfly-sum h1.phi over the 16 o16-lanes (bits 0..3)
            float tv = h1a * phiva + h1b * phivb;
#pragma unroll
            for (int mask = 1; mask < 16; mask <<= 1)
                tv += __shfl_xor(tv, mask, 64);
            if (r == 0 && o16 == 0) {
                const float bpos = h20 * (fh * (1.0f / 31.0f))
                                 + h21 * ((q * 16 + hc) * (1.0f / 63.0f));
                ws[OFF_V + b * 2048 + m] = tv - bpos;
            }
        }
    }

    // u[b,n] for the 64 full positions of this tile
    if (tid < 64) {
        const int r2 = tid >> 5, tl = tid & 31;
        float acc = 0.f;
        for (int c = 0; c < 64; ++c)
            acc += xs[c * 64 + r2 * 32 + tl] * wt_l[c];
        float tb_ = 0.f;
        for (int o2 = 0; o2 < 32; ++o2)
            tb_ += h0_w[o2] * theta_b[o2];
        const int f = 2 * fh + r2, tt = c0 + tl;
        const int n = f * 128 + tt;
        const float a = h20 * (f * (1.0f / 63.0f)) + h21 * (tt * (1.0f / 127.0f));
        ws[OFF_U + b * 8192 + n] = acc + tb_ + a;
    }
}

// ---------------------------------------------------------------------------
// Kernel 2: barrier-free rank sort (descending, index tie-break)
// 512 blocks x 256 thr. block=(b, chunk of 16 m's). Conflict-free strided walk.
// ---------------------------------------------------------------------------
__global__ __launch_bounds__(256) void k2()
{
    float* __restrict__ ws = g_ws;
    __shared__ __align__(16) float vl[2048];
    __shared__ int part[256];
    const int tid = threadIdx.x;
    const int b = blockIdx.x >> 7, chunk = blockIdx.x & 127;
    const float* v = ws + OFF_V + b * 2048;
    for (int i = tid; i < 2048; i += 256) vl[i] = v[i];
    __syncthreads();

    const int ml = tid >> 4;        // m within chunk [0,16)
    const int jq = tid & 15;        // j-segment [0,16)
    const int m = chunk * 16 + ml;
    const float vm = vl[m];
    int cnt = 0;
    const float4* v4 = (const float4*)vl;
#pragma unroll 4
    for (int i = 0; i < 32; ++i) {
        const int j4 = jq + 16 * i;          // wave reads consecutive float4s
        const float4 vv = v4[j4];
        const int jb = j4 * 4;
        cnt += (vv.x > vm) || (vv.x == vm && (jb    ) < m);
        cnt += (vv.y > vm) || (vv.y == vm && (jb + 1) < m);
        cnt += (vv.z > vm) || (vv.z == vm && (jb + 2) < m);
        cnt += (vv.w > vm) || (vv.w == vm && (jb + 3) < m);
    }
    part[tid] = cnt;
    __syncthreads();
    if (tid < 16) {
        int r = 0;
#pragma unroll
        for (int j = 0; j < 16; ++j) r += part[tid * 16 + j];
        ws[OFF_VS + b * 2048 + r] = vl[chunk * 16 + tid];
        g_perm[b * 2048 + r] = chunk * 16 + tid;
    }
}

// ---------------------------------------------------------------------------
// Kernel 3: z = W_w[o,:] . psi (sorted order), scan -> Q01[b][k][o] (float2)
// 256 blocks (b,o) x 512 thr, 4 items/thr. Shfl-scan + 1 barrier.
// ---------------------------------------------------------------------------
__global__ __launch_bounds__(512) void k3(const float* __restrict__ W_w)
{
    float* __restrict__ ws = g_ws;
    __shared__ float Wrow[32];
    __shared__ float wt0[8], wt1[8];
    const int tid = threadIdx.x;
    const int b = blockIdx.x >> 6, o = blockIdx.x & 63;
    if (tid < 32) Wrow[tid] = W_w[o * 33 + tid];   // W_w is (64,33); col 32 = zero channel
    __syncthreads();

    const int* perm = g_perm + b * 2048;
    const float* vs = ws + OFF_VS + b * 2048;
    const float* psi2 = ws + OFF_PSI2 + (size_t)b * 2048 * 32;

    float zl[4], vlv[4];
    float s0 = 0.f, s1 = 0.f;
    const int base = tid * 4;
#pragma unroll
    for (int qq = 0; qq < 4; ++qq) {
        const int i = base + qq;
        const int mp = perm[i];
        const float4* pr = (const float4*)(psi2 + (size_t)mp * 32);
        float z = 0.f;
#pragma unroll
        for (int w = 0; w < 8; ++w) {
            const float4 p4 = pr[w];
            z += Wrow[4 * w] * p4.x + Wrow[4 * w + 1] * p4.y
               + Wrow[4 * w + 2] * p4.z + Wrow[4 * w + 3] * p4.w;
        }
        const float vv = vs[i];
        zl[qq] = z; vlv[qq] = vv;
        s0 += z; s1 += vv * z;
    }

    // inclusive wave scan (64 lanes) of per-thread sums
    float w0 = s0, w1 = s1;
    const int lane = tid & 63, wv = tid >> 6;
#pragma unroll
    for (int off = 1; off < 64; off <<= 1) {
        const float t0_ = __shfl_up(w0, off, 64);
        const float t1_ = __shfl_up(w1, off, 64);
        if (lane >= off) { w0 += t0_; w1 += t1_; }
    }
    if (lane == 63) { wt0[wv] = w0; wt1[wv] = w1; }
    __syncthreads();
    float base0 = 0.f, base1 = 0.f;
    for (int w = 0; w < wv; ++w) { base0 += wt0[w]; base1 += wt1[w]; }
    float r0 = w0 + base0 - s0, r1 = w1 + base1 - s1;   // exclusive prefix

    float2* Q01 = (float2*)(ws + OFF_Q01) + (size_t)b * 2049 * 64;
#pragma unroll
    for (int qq = 0; qq < 4; ++qq) {
        r0 += zl[qq]; r1 += vlv[qq] * zl[qq];
        float2 p; p.x = r0; p.y = r1;
        Q01[(size_t)(base + qq + 1) * 64 + o] = p;
    }
    if (tid == 0) { float2 z2; z2.x = 0.f; z2.y = 0.f; Q01[o] = z2; }
}

// ---------------------------------------------------------------------------
// Kernel 4: stage sorted v in LDS, binary search k(n), gather Q01 rows
// (one dwordx2 per (n,lane)), fold W_b+BN, LDS transpose, add x, store.
// 512 blocks x 512 thr.
// ---------------------------------------------------------------------------
__global__ __launch_bounds__(512) void k4(
    const float* __restrict__ x,
    const float* __restrict__ W_b,
    const float* __restrict__ bn_g, const float* __restrict__ bn_b,
    const float* __restrict__ bn_m, const float* __restrict__ bn_v,
    float* __restrict__ out)
{
    const float* __restrict__ ws = g_ws;
    __shared__ __align__(16) float vsl[2048];
    __shared__ float tileb[64 * 65];   // [o][n] pitch 65
    __shared__ int karr[64];
    __shared__ float uarr[64];

    const int tid = threadIdx.x;
    const int b = blockIdx.x >> 7, tile = blockIdx.x & 127;
    const int n0 = tile * 64;

    const float* vs = ws + OFF_VS + b * 2048;
    for (int i = tid; i < 2048; i += 512) vsl[i] = vs[i];
    __syncthreads();

    if (tid < 64) {
        const float u = ws[OFF_U + b * 8192 + n0 + tid];
        const float thr = -u;
        int lo = 0, hi = 2048;
        while (lo < hi) {                  // first idx with vsl[idx] <= -u (descending)
            const int mid = (lo + hi) >> 1;
            if (vsl[mid] > thr) lo = mid + 1; else hi = mid;
        }
        karr[tid] = lo;
        uarr[tid] = u;
    }
    __syncthreads();

    const int lane = tid & 63, w = tid >> 6;   // w in [0,8)
    const float inv = bn_g[lane] * __frsqrt_rn(bn_v[lane] + 1e-5f);
    const float sft = W_b[lane] * inv + bn_b[lane] - bn_m[lane] * inv;
    const float2* Q01 = (const float2*)(ws + OFF_Q01) + (size_t)b * 2049 * 64;

    for (int nl = w; nl < 64; nl += 8) {
        const int k = karr[nl];
        const float u = uarr[nl];
        const float2 qv = Q01[(size_t)k * 64 + lane];  // 512B coalesced row
        const float raw = (u * qv.x + qv.y) * (1.0f / 2048.0f);
        tileb[lane * 65 + nl] = raw * inv + sft;       // 2-way bank aliasing: free
    }
    __syncthreads();

    for (int idx = tid; idx < 2048; idx += 512) {      // float2 epilogue
        const int o = idx >> 5, j2 = idx & 31;
        const size_t gi = ((size_t)b * 64 + o) * 8192 + n0 + 2 * j2;
        const float2 xv = *(const float2*)&x[gi];
        float2 r;
        r.x = tileb[o * 65 + 2 * j2] + xv.x;
        r.y = tileb[o * 65 + 2 * j2 + 1] + xv.y;
        *(float2*)&out[gi] = r;
    }
}

// ---------------------------------------------------------------------------
extern "C" void kernel_launch(void* const* d_in, const int* in_sizes, int n_in,
                              void* d_out, int out_size, void* d_ws, size_t ws_size,
                              hipStream_t stream)
{
    (void)in_sizes; (void)n_in; (void)out_size; (void)d_ws; (void)ws_size;
    const float* x       = (const float*)d_in[0];
    const float* psi_w   = (const float*)d_in[1];
    const float* psi_b   = (const float*)d_in[2];
    const float* theta_w = (const float*)d_in[3];
    const float* theta_b = (const float*)d_in[4];
    const float* phi_w   = (const float*)d_in[5];
    const float* phi_b   = (const float*)d_in[6];
    const float* h0_w    = (const float*)d_in[7];
    const float* h1_w    = (const float*)d_in[8];
    const float* h2_w    = (const float*)d_in[9];
    const float* W_w     = (const float*)d_in[10];
    const float* W_b     = (const float*)d_in[11];
    const float* bn_g    = (const float*)d_in[12];
    const float* bn_b    = (const float*)d_in[13];
    const float* bn_m    = (const float*)d_in[14];
    const float* bn_v    = (const float*)d_in[15];
    float* out = (float*)d_out;

    k1<<<dim3(512), dim3(256), 0, stream>>>(x, psi_w, psi_b, theta_w, theta_b,
                                            phi_w, phi_b, h0_w, h1_w, h2_w);
    k2<<<dim3(512), dim3(256), 0, stream>>>();
    k3<<<dim3(256), dim3(512), 0, stream>>>(W_w);
    k4<<<dim3(512), dim3(512), 0, stream>>>(x, W_b, bn_g, bn_b, bn_m, bn_v, out);
}